// Round 1
// baseline (470.151 us; speedup 1.0000x reference)
//
#include <hip/hip_runtime.h>

// Problem constants
#define B_  4
#define C_  8
#define T_  512
#define F_  512
#define H_  8
#define M_  (B_*C_*T_)   // 16384 rows

typedef unsigned short u16;
typedef unsigned int   u32;
typedef __bf16 bf16x8 __attribute__((ext_vector_type(8)));
typedef float  f32x4  __attribute__((ext_vector_type(4)));

// ---------- bf16 helpers ----------
__device__ __forceinline__ float bf2f(u16 s) {
    union { u32 u; float f; } c; c.u = ((u32)s) << 16; return c.f;
}
__device__ __forceinline__ u16 f2bf(float f) {
    union { float f; u32 u; } c; c.f = f;
    u32 r = c.u + 0x7fffu + ((c.u >> 16) & 1u);   // RNE
    return (u16)(r >> 16);
}
__device__ __forceinline__ float bflo(u32 v){ union{u32 u; float f;} c; c.u = v << 16;        return c.f; }
__device__ __forceinline__ float bfhi(u32 v){ union{u32 u; float f;} c; c.u = v & 0xffff0000u; return c.f; }

// async global->LDS, 16 B per lane. lds must be the wave-uniform base.
__device__ __forceinline__ void async16(u16* lds, const u16* g) {
    __builtin_amdgcn_global_load_lds(
        (const __attribute__((address_space(1))) u32*)g,
        (__attribute__((address_space(3))) u32*)lds,
        16, 0, 0);
}

// ---------------------------------------------------------------------
// K0: fp32 -> bf16 convert, 6 tensors.
// v2: 16 B coalesced uint4 stores; 8 float4 loads issued back-to-back
// per thread (8-deep MLP ILP, ~40 VGPR) instead of the old serialized
// load->wait->store chain at VGPR_Count=8 with 8 B stores.
// Each thread: 4 output uint4 (32 floats). Per-tensor uint4 = 1Mi,
// grid.x = 1024 blocks * 256 thr * 4 = 1Mi.
// ---------------------------------------------------------------------
struct ConvArgs { const float* src[6]; u16* dst[6]; };

__global__ __launch_bounds__(256)
void convert6_kernel(ConvArgs a)
{
    const int tid  = threadIdx.x;
    const int base = blockIdx.x * 1024 + tid;            // uint4 index
    const float4* s = (const float4*)a.src[blockIdx.y];
    uint4*        d = (uint4*)a.dst[blockIdx.y];

    float4 v[8];
    #pragma unroll
    for (int k = 0; k < 4; ++k) {
        const int o = base + (k << 8);
        v[2*k]     = s[2*o];
        v[2*k + 1] = s[2*o + 1];
    }
    #pragma unroll
    for (int k = 0; k < 4; ++k) {
        const int o = base + (k << 8);
        uint4 u;
        u.x = (u32)f2bf(v[2*k].x)   | ((u32)f2bf(v[2*k].y)   << 16);
        u.y = (u32)f2bf(v[2*k].z)   | ((u32)f2bf(v[2*k].w)   << 16);
        u.z = (u32)f2bf(v[2*k+1].x) | ((u32)f2bf(v[2*k+1].y) << 16);
        u.w = (u32)f2bf(v[2*k+1].z) | ((u32)f2bf(v[2*k+1].w) << 16);
        d[o] = u;
    }
}

// ---------------------------------------------------------------------
// Kp: build WbigBT (1024x1024 bf16, [n][k]) and biasBig (1024 fp32) per stage.
// ---------------------------------------------------------------------
struct PrepArgs { const float* wr[4]; const float* wi[4]; const float* br[4]; const float* bi[4]; };

__global__ __launch_bounds__(256)
void prep_weights_kernel(PrepArgs a, u16* __restrict__ wbig, float* __restrict__ bbig)
{
    const int s   = blockIdx.y;
    const int idx = blockIdx.x * 256 + threadIdx.x;   // 0 .. 262143
    const int n   = idx >> 8;                         // 0..1023
    const int k0  = (idx & 255) << 2;                 // 0..1020
    const int nn = n & 511, kk = k0 & 511;
    const float* src; float sgn = 1.0f;
    if (n < 512) { if (k0 < 512) src = a.wr[s]; else { src = a.wi[s]; sgn = -1.0f; } }
    else         { if (k0 < 512) src = a.wi[s]; else   src = a.wr[s]; }
    const float4 v = *(const float4*)(src + (size_t)nn * 512 + kk);
    ushort4 q;
    q.x = f2bf(sgn * v.x); q.y = f2bf(sgn * v.y);
    q.z = f2bf(sgn * v.z); q.w = f2bf(sgn * v.w);
    *(ushort4*)(wbig + (size_t)s * 1048576 + (size_t)n * 1024 + k0) = q;

    if (blockIdx.x < 4) {
        const int bidx = blockIdx.x * 256 + threadIdx.x;   // 0..1023
        const float brv = a.br[s][bidx & 511];
        const float biv = a.bi[s][bidx & 511];
        bbig[s * 1024 + bidx] = (bidx < 512) ? (brv - biv) : (brv + biv);
    }
}

// ---------------------------------------------------------------------
// MFMA complex-linear as packed real GEMM:
//   Y[m,n] = sum_k Xcat[m,k] * WbigBT[n,k] + biasBig[n]
// Tile 128x128, BK=64 done as TWO BK=32 panels per barrier (halves the
// __syncthreads/vmcnt-drain count; keeps the proven 64B-row-stride LDS
// layout -> only free 2-way bank aliasing). 256 threads, 4 waves, each
// 64x64 = 4x4 MFMA tiles. LDS staging 32KB; PERM epilogue reuses smem
// (128x136 bf16 C-tile -> coalesced 16B stores in attention layout).
// __launch_bounds__(256,4): all 1024 blocks co-resident, no tail round.
// ---------------------------------------------------------------------
template <bool PERM_OUT, bool LRELU, bool OUT_F32>
__global__ __launch_bounds__(256, 4)
void mfma_clinear_kernel(const u16* __restrict__ Ar, const u16* __restrict__ Ai,
                         const u16* __restrict__ Wbt, const float* __restrict__ bias,
                         void* __restrict__ Yr_, void* __restrict__ Yi_)
{
    constexpr int SMEM_ELEMS = PERM_OUT ? (128 * 136) : (128 * 128);
    __shared__ __align__(16) u16 smem[SMEM_ELEMS];
    u16* sA = smem;               // 2 panels of [128][32]
    u16* sB = smem + 8192;        // 2 panels of [128][32]

    const int tid  = threadIdx.x;
    const int wave = tid >> 6;
    const int lane = tid & 63;
    const int m0   = blockIdx.x << 7;
    const int n0   = blockIdx.y << 7;
    const int mw   = (wave >> 1) << 6;   // 0 / 64
    const int nw   = (wave & 1) << 6;    // 0 / 64

    const int srow = tid >> 2;           // 0..63
    const int sk   = (tid & 3) << 3;     // 0,8,16,24
    const size_t arow0 = (size_t)(m0 + srow) * 512;
    const size_t arow1 = (size_t)(m0 + 64 + srow) * 512;
    const size_t brow0 = (size_t)(n0 + srow) * 1024;
    const size_t brow1 = (size_t)(n0 + 64 + srow) * 1024;

    u16* ldsA = sA + (wave << 9);
    u16* ldsB = sB + (wave << 9);

    f32x4 acc[4][4] = {};

    const int fr = lane & 15;            // fragment row (m or n)
    const int fq = (lane >> 4) << 3;     // fragment k offset

    for (int k0 = 0; k0 < 1024; k0 += 64) {
        const u16* As = (k0 < 512) ? Ar : Ai;
        const int  ak = (k0 & 511) + sk;
        __syncthreads();
        #pragma unroll
        for (int p = 0; p < 2; ++p) {
            const int kp = p << 5;
            async16(ldsA + p * 4096,        As + arow0 + ak + kp);
            async16(ldsA + p * 4096 + 2048, As + arow1 + ak + kp);
            async16(ldsB + p * 4096,        Wbt + brow0 + k0 + sk + kp);
            async16(ldsB + p * 4096 + 2048, Wbt + brow1 + k0 + sk + kp);
        }
        __syncthreads();

        #pragma unroll
        for (int p = 0; p < 2; ++p) {
            bf16x8 af[4], bfr[4];
            #pragma unroll
            for (int i = 0; i < 4; ++i)
                af[i] = *(const bf16x8*)&sA[p * 4096 + (mw + i * 16 + fr) * 32 + fq];
            #pragma unroll
            for (int j = 0; j < 4; ++j)
                bfr[j] = *(const bf16x8*)&sB[p * 4096 + (nw + j * 16 + fr) * 32 + fq];

            #pragma unroll
            for (int i = 0; i < 4; ++i)
                #pragma unroll
                for (int j = 0; j < 4; ++j)
                    acc[i][j] = __builtin_amdgcn_mfma_f32_16x16x32_bf16(af[i], bfr[j], acc[i][j], 0, 0, 0);
        }
    }

    const int col_l = lane & 15;
    const int row_l = (lane >> 4) << 2;

    if constexpr (PERM_OUT) {
        // ---- stage C tile (bf16) in LDS, then coalesced 16B stores ----
        constexpr int LDN = 136;         // pad 128 -> 136 (conflict-light)
        __syncthreads();                 // main-loop LDS reads all done
        #pragma unroll
        for (int j = 0; j < 4; ++j) {
            const int ncl = nw + (j << 4) + col_l;      // 0..127 within tile
            const float bv = bias[n0 + ncl];
            #pragma unroll
            for (int i = 0; i < 4; ++i) {
                const int mrow = mw + (i << 4) + row_l;
                #pragma unroll
                for (int r = 0; r < 4; ++r) {
                    float v = acc[i][j][r] + bv;
                    if constexpr (LRELU) v = v >= 0.f ? v : 0.01f * v;
                    smem[(mrow + r) * LDN + ncl] = f2bf(v);
                }
            }
        }
        __syncthreads();
        u16* Yr = (u16*)Yr_;
        u16* Yi = (u16*)Yi_;
        #pragma unroll
        for (int s = 0; s < 8; ++s) {
            const int idx = (s << 8) + tid;     // 0..2047
            const int ml  = idx >> 4;           // 0..127
            const int c8  = (idx & 15) << 3;    // 0,8,..,120
            const uint4 dv = *(const uint4*)&smem[ml * LDN + c8];
            const int m    = m0 + ml;
            const int ncol = n0 + c8;
            const int part = ncol >> 9;
            const int nc   = ncol & 511;
            const int bb = m >> 12, cc = (m >> 9) & 7, tt = m & 511;
            const int hh = nc >> 6, dd = nc & 63;
            const size_t addr = ((size_t)(((bb << 3) + hh) * T_ + tt) << 9) + (cc << 6) + dd;
            u16* Y = part ? Yi : Yr;
            *(uint4*)(Y + addr) = dv;
        }
    } else {
        // ---- direct fp32 stores (64B segments per 16-lane group) ----
        #pragma unroll
        for (int j = 0; j < 4; ++j) {
            const int ncol = n0 + nw + (j << 4) + col_l;
            const float bv = bias[ncol];
            const int part = ncol >> 9;
            const int nc   = ncol & 511;
            float* Y = part ? (float*)Yi_ : (float*)Yr_;
            #pragma unroll
            for (int i = 0; i < 4; ++i) {
                const int mbase = m0 + mw + (i << 4) + row_l;
                #pragma unroll
                for (int r = 0; r < 4; ++r) {
                    float v = acc[i][j][r] + bv;
                    if constexpr (LRELU) v = v >= 0.f ? v : 0.01f * v;
                    Y[(size_t)(mbase + r) * 512 + nc] = v;
                }
            }
        }
    }
}

// ---------------------------------------------------------------------
// Attention: per (b,h,t) chunk w = (b*H+h)*T + t, matrices stored as
// 512 contiguous bf16 (c*64+d) at offset w*512.
// ---------------------------------------------------------------------
__global__ __launch_bounds__(256)
void attn_kernel(const u16* __restrict__ qr, const u16* __restrict__ qi,
                 const u16* __restrict__ kr, const u16* __restrict__ ki,
                 const u16* __restrict__ vr, const u16* __restrict__ vi,
                 u16* __restrict__ xr, u16* __restrict__ xi)
{
    constexpr int RS = 68;        // padded row stride (floats)
    constexpr int MS = 8 * RS;    // per matrix: 544 floats
    __shared__ float L[4][6 * MS];     // 52224 B
    __shared__ float S[4][128];        // sr(64) + si(64) per wave

    const int wave = threadIdx.x >> 6;
    const int lane = threadIdx.x & 63;
    const int w    = (blockIdx.x << 2) + wave;   // (b*H+h)*T + t
    const int cl   = lane >> 3;                  // c-index 0..7
    const int dl   = lane & 7;                   // 0..7
    const int d0   = dl << 3;                    // 0,8,..,56

    float* Lw = L[wave];
    const u16* srcs[6] = {qr, qi, kr, ki, vr, vi};
    const size_t gbase = ((size_t)w << 9) + (lane << 3);
    #pragma unroll
    for (int m2 = 0; m2 < 6; ++m2) {
        const uint4 u = *(const uint4*)(srcs[m2] + gbase);
        float* dst = Lw + m2 * MS + cl * RS + d0;
        dst[0]=bflo(u.x); dst[1]=bfhi(u.x);
        dst[2]=bflo(u.y); dst[3]=bfhi(u.y);
        dst[4]=bflo(u.z); dst[5]=bfhi(u.z);
        dst[6]=bflo(u.w); dst[7]=bfhi(u.w);
    }
    __syncthreads();

    { // scores: lane -> (c=cl, e=dl)
        const float* Qr = Lw + 0*MS + cl*RS;
        const float* Qi = Lw + 1*MS + cl*RS;
        const float* Kr = Lw + 2*MS + dl*RS;
        const float* Ki = Lw + 3*MS + dl*RS;
        float srr=0.f, sii=0.f, sri=0.f, sir=0.f;
        #pragma unroll 8
        for (int d = 0; d < 64; ++d) {
            srr = fmaf(Qr[d], Kr[d], srr);
            sii = fmaf(Qi[d], Ki[d], sii);
            sri = fmaf(Qr[d], Ki[d], sri);
            sir = fmaf(Qi[d], Kr[d], sir);
        }
        S[wave][lane]      = (srr + sii) * 0.125f;   // sr[c][e]
        S[wave][64 + lane] = (sri - sir) * 0.125f;   // si[c][e]
    }
    __syncthreads();

    const float* Vr = Lw + 4*MS;
    const float* Vi = Lw + 5*MS;
    const float* Sr = S[wave];
    const float* Si = S[wave] + 64;
    float outr[8] = {}, outi[8] = {};
    #pragma unroll
    for (int e = 0; e < 8; ++e) {
        const float sre = Sr[(cl<<3) + e];
        const float sie = Si[(cl<<3) + e];
        const float* vre = Vr + e*RS + d0;
        const float* vie = Vi + e*RS + d0;
        #pragma unroll
        for (int j = 0; j < 8; ++j) {
            outr[j] = fmaf(sre,  vre[j], outr[j]);
            outr[j] = fmaf(-sie, vie[j], outr[j]);
            outi[j] = fmaf(sie,  vre[j], outi[j]);
            outi[j] = fmaf(sre,  vie[j], outi[j]);
        }
    }

    // write merged (B,C,T,F) bf16 with lrelu
    const int tt = w & 511, hh = (w >> 9) & 7, bb = w >> 12;
    const size_t obase = ((size_t)(((bb << 3) + cl) * T_ + tt) << 9) + (hh << 6) + d0;
    u32 pr[4], pi[4];
    #pragma unroll
    for (int jj = 0; jj < 4; ++jj) {
        float r0 = outr[2*jj], r1 = outr[2*jj+1];
        float i0 = outi[2*jj], i1 = outi[2*jj+1];
        r0 = r0 >= 0.f ? r0 : 0.01f*r0;  r1 = r1 >= 0.f ? r1 : 0.01f*r1;
        i0 = i0 >= 0.f ? i0 : 0.01f*i0;  i1 = i1 >= 0.f ? i1 : 0.01f*i1;
        pr[jj] = (u32)f2bf(r0) | ((u32)f2bf(r1) << 16);
        pi[jj] = (u32)f2bf(i0) | ((u32)f2bf(i1) << 16);
    }
    *(uint4*)(xr + obase) = make_uint4(pr[0], pr[1], pr[2], pr[3]);
    *(uint4*)(xi + obase) = make_uint4(pi[0], pi[1], pi[2], pi[3]);
}

// ---------------------------------------------------------------------
extern "C" void kernel_launch(void* const* d_in, const int* in_sizes, int n_in,
                              void* d_out, int out_size, void* d_ws, size_t ws_size,
                              hipStream_t stream)
{
    (void)in_sizes; (void)n_in; (void)out_size; (void)ws_size;
    const float* act[6];
    for (int i = 0; i < 6; ++i) act[i] = (const float*)d_in[i];

    PrepArgs pa;
    for (int s = 0; s < 4; ++s) {
        pa.wr[s] = (const float*)d_in[6 + s*4 + 0];
        pa.br[s] = (const float*)d_in[6 + s*4 + 1];
        pa.wi[s] = (const float*)d_in[6 + s*4 + 2];
        pa.bi[s] = (const float*)d_in[6 + s*4 + 3];
    }

    const size_t SZ = (size_t)M_ * F_;        // 8,388,608 elements
    u16* ws = (u16*)d_ws;
    u16* a0 = ws + 0*SZ;  u16* a1 = ws + 1*SZ;   // query bf16 -> later k outputs
    u16* a2 = ws + 2*SZ;  u16* a3 = ws + 3*SZ;   // key bf16   -> later v outputs
    u16* a4 = ws + 4*SZ;  u16* a5 = ws + 5*SZ;   // value bf16 -> later attn outputs
    u16* q0 = ws + 6*SZ;  u16* q1 = ws + 7*SZ;   // q outputs
    u16*   wbig = ws + 8*SZ;                      // 4 x 1M bf16
    float* bbig = (float*)(wbig + 4u*1024*1024);  // 4 x 1024 fp32

    ConvArgs ca;
    ca.src[0]=act[0]; ca.src[1]=act[1]; ca.src[2]=act[2];
    ca.src[3]=act[3]; ca.src[4]=act[4]; ca.src[5]=act[5];
    ca.dst[0]=a0; ca.dst[1]=a1; ca.dst[2]=a2; ca.dst[3]=a3; ca.dst[4]=a4; ca.dst[5]=a5;

    convert6_kernel<<<dim3(1024, 6), 256, 0, stream>>>(ca);
    prep_weights_kernel<<<dim3(1024, 4), 256, 0, stream>>>(pa, wbig, bbig);

    dim3 ggrid(M_/128, 1024/128);
    // q stage
    mfma_clinear_kernel<true,  false, false><<<ggrid, 256, 0, stream>>>(
        a0, a1, wbig + 0u*1048576, bbig + 0*1024, q0, q1);
    // k stage (writes into a0/a1, already consumed)
    mfma_clinear_kernel<true,  false, false><<<ggrid, 256, 0, stream>>>(
        a2, a3, wbig + 1u*1048576, bbig + 1*1024, a0, a1);
    // v stage with leaky-relu (writes into a2/a3)
    mfma_clinear_kernel<true,  true,  false><<<ggrid, 256, 0, stream>>>(
        a4, a5, wbig + 2u*1048576, bbig + 2*1024, a2, a3);

    // attention: q=q0/q1, k=a0/a1, v=a2/a3 -> merged xr=a4, xi=a5
    attn_kernel<<<dim3((B_*H_*T_)/4), 256, 0, stream>>>(q0, q1, a0, a1, a2, a3, a4, a5);

    // output stage: fp32 out, no perm, no lrelu
    float* out_r = (float*)d_out;
    mfma_clinear_kernel<false, false, true><<<ggrid, 256, 0, stream>>>(
        a4, a5, wbig + 3u*1048576, bbig + 3*1024, out_r, out_r + SZ);
}

// Round 2
// 441.901 us; speedup vs baseline: 1.0639x; 1.0639x over previous
//
#include <hip/hip_runtime.h>

// Problem constants
#define B_  4
#define C_  8
#define T_  512
#define F_  512
#define H_  8
#define M_  (B_*C_*T_)   // 16384 rows

typedef unsigned short u16;
typedef unsigned int   u32;
typedef __bf16 bf16x8 __attribute__((ext_vector_type(8)));
typedef float  f32x4  __attribute__((ext_vector_type(4)));

// ---------- bf16 helpers ----------
__device__ __forceinline__ float bf2f(u16 s) {
    union { u32 u; float f; } c; c.u = ((u32)s) << 16; return c.f;
}
__device__ __forceinline__ u16 f2bf(float f) {
    union { float f; u32 u; } c; c.f = f;
    u32 r = c.u + 0x7fffu + ((c.u >> 16) & 1u);   // RNE
    return (u16)(r >> 16);
}
__device__ __forceinline__ float bflo(u32 v){ union{u32 u; float f;} c; c.u = v << 16;        return c.f; }
__device__ __forceinline__ float bfhi(u32 v){ union{u32 u; float f;} c; c.u = v & 0xffff0000u; return c.f; }

// async global->LDS, 16 B per lane. lds must be the wave-uniform base.
__device__ __forceinline__ void async16(u16* lds, const u16* g) {
    __builtin_amdgcn_global_load_lds(
        (const __attribute__((address_space(1))) u32*)g,
        (__attribute__((address_space(3))) u32*)lds,
        16, 0, 0);
}

// ---------------------------------------------------------------------
// K0: fp32 -> bf16 convert, 6 tensors. (pinned at ~2.2 TB/s HBM by
// mixed-stream DRAM behavior — two different structures measured equal;
// leave as-is)
// ---------------------------------------------------------------------
struct ConvArgs { const float* src[6]; u16* dst[6]; };

__global__ __launch_bounds__(256)
void convert6_kernel(ConvArgs a)
{
    const int tid  = threadIdx.x;
    const int base = blockIdx.x * 1024 + tid;            // uint4 index
    const float4* s = (const float4*)a.src[blockIdx.y];
    uint4*        d = (uint4*)a.dst[blockIdx.y];

    float4 v[8];
    #pragma unroll
    for (int k = 0; k < 4; ++k) {
        const int o = base + (k << 8);
        v[2*k]     = s[2*o];
        v[2*k + 1] = s[2*o + 1];
    }
    #pragma unroll
    for (int k = 0; k < 4; ++k) {
        const int o = base + (k << 8);
        uint4 u;
        u.x = (u32)f2bf(v[2*k].x)   | ((u32)f2bf(v[2*k].y)   << 16);
        u.y = (u32)f2bf(v[2*k].z)   | ((u32)f2bf(v[2*k].w)   << 16);
        u.z = (u32)f2bf(v[2*k+1].x) | ((u32)f2bf(v[2*k+1].y) << 16);
        u.w = (u32)f2bf(v[2*k+1].z) | ((u32)f2bf(v[2*k+1].w) << 16);
        d[o] = u;
    }
}

// ---------------------------------------------------------------------
// Kp: build WbigBT (1024x1024 bf16, [n][k]) and biasBig (1024 fp32) per stage.
// ---------------------------------------------------------------------
struct PrepArgs { const float* wr[4]; const float* wi[4]; const float* br[4]; const float* bi[4]; };

__global__ __launch_bounds__(256)
void prep_weights_kernel(PrepArgs a, u16* __restrict__ wbig, float* __restrict__ bbig)
{
    const int s   = blockIdx.y;
    const int idx = blockIdx.x * 256 + threadIdx.x;   // 0 .. 262143
    const int n   = idx >> 8;                         // 0..1023
    const int k0  = (idx & 255) << 2;                 // 0..1020
    const int nn = n & 511, kk = k0 & 511;
    const float* src; float sgn = 1.0f;
    if (n < 512) { if (k0 < 512) src = a.wr[s]; else { src = a.wi[s]; sgn = -1.0f; } }
    else         { if (k0 < 512) src = a.wi[s]; else   src = a.wr[s]; }
    const float4 v = *(const float4*)(src + (size_t)nn * 512 + kk);
    ushort4 q;
    q.x = f2bf(sgn * v.x); q.y = f2bf(sgn * v.y);
    q.z = f2bf(sgn * v.z); q.w = f2bf(sgn * v.w);
    *(ushort4*)(wbig + (size_t)s * 1048576 + (size_t)n * 1024 + k0) = q;

    if (blockIdx.x < 4) {
        const int bidx = blockIdx.x * 256 + threadIdx.x;   // 0..1023
        const float brv = a.br[s][bidx & 511];
        const float biv = a.bi[s][bidx & 511];
        bbig[s * 1024 + bidx] = (bidx < 512) ? (brv - biv) : (brv + biv);
    }
}

// ---------------------------------------------------------------------
// 256x256-tile 8-wave GEMM with 4-phase counted-vmcnt pipeline (T2+T3+T4+T5).
//   Y[m,n] = sum_k Xcat[m,k] * WbigBT[n,k] + biasBig[n]
// Grid 64x4 = 256 blocks = 1 block/CU. BK=64, 16 K-tiles, double-buffered
// 128 KiB LDS. Per K-tile: 4 phases, each {ds_read A-quad (+B in p0),
// issue 2 global_load_lds for tile t+1, s_barrier, setprio(1), 16 MFMA,
// setprio(0), [vmcnt(4)@p1 / vmcnt(2)@p3], s_barrier}. vmcnt never
// drained to 0 in steady state (T4). LDS linear [256][64] bf16 with
// byte ^= (row&7)<<4 XOR swizzle applied via PRE-SWIZZLED global source
// (rule #21: gload_lds writes linearly) and swizzled ds_read addresses.
// Issue order per tile: B0,B1 | B2,B3 | A0,A2 | A1,A3 so that at the
// boundary wait vmcnt(2) only A1,A3 (needed at phases 2-3) are in flight.
// ---------------------------------------------------------------------
template <bool PERM_OUT, bool LRELU>
__global__ __launch_bounds__(512, 2)
void mfma_clinear256_kernel(const u16* __restrict__ Ar, const u16* __restrict__ Ai,
                            const u16* __restrict__ Wbt, const float* __restrict__ bias,
                            void* __restrict__ Yr_, void* __restrict__ Yi_)
{
    constexpr int SMEM_U16 = PERM_OUT ? (256 * 272) : (256 * 256);
    __shared__ __align__(16) u16 smem[SMEM_U16];
    char* const sm = (char*)smem;

    const int tid  = threadIdx.x;
    const int wv   = tid >> 6;
    const int lane = tid & 63;
    const int m0   = blockIdx.x << 8;
    const int n0   = blockIdx.y << 8;
    const int wm   = (wv >> 2) << 7;       // 0 / 128
    const int wn   = (wv & 3) << 6;        // 0 / 64 / 128 / 192

    const int frow = lane & 15;            // fragment row within 16
    const int fkb  = (lane >> 4) << 4;     // fragment k byte offset 0/16/32/48

    const int srow = tid >> 3;                         // staging row 0..63
    const int scol = ((tid & 7) ^ (srow & 7)) << 3;    // pre-swizzled col (elems)
    const int ldst = wv << 10;                         // wave base within 8KB issue

    f32x4 acc[8][4] = {};
    bf16x8 bq[4][2];

    // ---- prologue: stage K-tile 0 into buffer 0; order B0..B3, A0,A2,A1,A3
    {
        #pragma unroll
        for (int b = 0; b < 4; ++b)
            async16((u16*)(sm + 65536 + b * 8192 + ldst),
                    Wbt + (size_t)(n0 + b * 64 + srow) * 1024 + scol);
        async16((u16*)(sm + 0 * 8192 + ldst), Ar + (size_t)(m0 +   0 + srow) * 512 + scol);
        async16((u16*)(sm + 2 * 8192 + ldst), Ar + (size_t)(m0 + 128 + srow) * 512 + scol);
        async16((u16*)(sm + 1 * 8192 + ldst), Ar + (size_t)(m0 +  64 + srow) * 512 + scol);
        async16((u16*)(sm + 3 * 8192 + ldst), Ar + (size_t)(m0 + 192 + srow) * 512 + scol);
        asm volatile("s_waitcnt vmcnt(2)" ::: "memory");
        asm volatile("s_barrier" ::: "memory");
    }

    for (int tt = 0; tt < 16; ++tt) {
        char* const curA = sm + ((tt & 1) << 15);
        char* const curB = sm + 65536 + ((tt & 1) << 15);
        char* const nxtA = sm + (((tt + 1) & 1) << 15);
        char* const nxtB = sm + 65536 + (((tt + 1) & 1) << 15);
        const bool more = (tt + 1) < 16;
        const u16* An  = ((tt + 1) < 8) ? Ar : Ai;
        const int  akc = ((tt + 1) & 7) << 6;   // next-tile A col (elems)
        const int  bkc = (tt + 1) << 6;         // next-tile B col (elems)

        #pragma unroll
        for (int q = 0; q < 4; ++q) {
            // ds_read A-quad q (4 x b128), swizzled
            bf16x8 aq[2][2];
            #pragma unroll
            for (int i = 0; i < 2; ++i) {
                const int ra = wm + (2 * q + i) * 16 + frow;
                #pragma unroll
                for (int kk = 0; kk < 2; ++kk) {
                    const int cb = (kk << 6) + fkb;
                    aq[i][kk] = *(const bf16x8*)(curA + ra * 128 + (cb ^ ((ra & 7) << 4)));
                }
            }
            if (q == 0) {   // B frags for the whole tile (8 x b128), held in regs
                #pragma unroll
                for (int nf = 0; nf < 4; ++nf) {
                    const int rb = wn + nf * 16 + frow;
                    #pragma unroll
                    for (int kk = 0; kk < 2; ++kk) {
                        const int cb = (kk << 6) + fkb;
                        bq[nf][kk] = *(const bf16x8*)(curB + rb * 128 + (cb ^ ((rb & 7) << 4)));
                    }
                }
            }
            // stage 2 issues of K-tile tt+1 (pre-swizzled source, linear dest)
            if (more) {
                if (q == 0) {
                    async16((u16*)(nxtB + 0 * 8192 + ldst), Wbt + (size_t)(n0 +   0 + srow) * 1024 + bkc + scol);
                    async16((u16*)(nxtB + 1 * 8192 + ldst), Wbt + (size_t)(n0 +  64 + srow) * 1024 + bkc + scol);
                } else if (q == 1) {
                    async16((u16*)(nxtB + 2 * 8192 + ldst), Wbt + (size_t)(n0 + 128 + srow) * 1024 + bkc + scol);
                    async16((u16*)(nxtB + 3 * 8192 + ldst), Wbt + (size_t)(n0 + 192 + srow) * 1024 + bkc + scol);
                } else if (q == 2) {
                    async16((u16*)(nxtA + 0 * 8192 + ldst), An + (size_t)(m0 +   0 + srow) * 512 + akc + scol);
                    async16((u16*)(nxtA + 2 * 8192 + ldst), An + (size_t)(m0 + 128 + srow) * 512 + akc + scol);
                } else {
                    async16((u16*)(nxtA + 1 * 8192 + ldst), An + (size_t)(m0 +  64 + srow) * 512 + akc + scol);
                    async16((u16*)(nxtA + 3 * 8192 + ldst), An + (size_t)(m0 + 192 + srow) * 512 + akc + scol);
                }
            }
            asm volatile("s_barrier" ::: "memory");
            __builtin_amdgcn_s_setprio(1);
            #pragma unroll
            for (int kk = 0; kk < 2; ++kk)
                #pragma unroll
                for (int i = 0; i < 2; ++i)
                    #pragma unroll
                    for (int nf = 0; nf < 4; ++nf)
                        acc[2 * q + i][nf] = __builtin_amdgcn_mfma_f32_16x16x32_bf16(
                            aq[i][kk], bq[nf][kk], acc[2 * q + i][nf], 0, 0, 0);
            __builtin_amdgcn_s_setprio(0);
            if (q == 1) {        // before phases 2-3 read A blks 1,3 of CURRENT tile
                if (more) asm volatile("s_waitcnt vmcnt(4)" ::: "memory");
                else      asm volatile("s_waitcnt vmcnt(0)" ::: "memory");
            } else if (q == 3) { // tile boundary: next tile's B + A0,A2 must be in
                if (more) asm volatile("s_waitcnt vmcnt(2)" ::: "memory");
                else      asm volatile("s_waitcnt vmcnt(0)" ::: "memory");
            }
            asm volatile("s_barrier" ::: "memory");
        }
    }

    const int row_l = (lane >> 4) << 2;

    if constexpr (PERM_OUT) {
        // ---- stage C tile (bf16) in LDS, then coalesced permuted 16B stores ----
        constexpr int LDN = 272;   // 544 B row stride: 16B-aligned rows, conflict-free writes
        #pragma unroll
        for (int mf = 0; mf < 8; ++mf) {
            const int mr = wm + mf * 16 + row_l;
            #pragma unroll
            for (int nf = 0; nf < 4; ++nf) {
                const int ncl = wn + nf * 16 + frow;
                const float bv = bias[n0 + ncl];
                #pragma unroll
                for (int r = 0; r < 4; ++r) {
                    float v = acc[mf][nf][r] + bv;
                    if constexpr (LRELU) v = v >= 0.f ? v : 0.01f * v;
                    smem[(mr + r) * LDN + ncl] = f2bf(v);
                }
            }
        }
        __syncthreads();
        const int part = n0 >> 9;                 // uniform per block (BN=256)
        u16* Y = part ? (u16*)Yi_ : (u16*)Yr_;
        #pragma unroll
        for (int it = 0; it < 16; ++it) {
            const int idx = (it << 9) + tid;      // 0..8191
            const int ml  = idx >> 5;             // 0..255
            const int c8  = (idx & 31) << 3;      // 0,8,..,248
            const uint4 dv = *(const uint4*)&smem[ml * LDN + c8];
            const int m  = m0 + ml;
            const int nc = (n0 + c8) & 511;
            const int bb = m >> 12, cc = (m >> 9) & 7, tq = m & 511;
            const int hh = nc >> 6, dd = nc & 63;
            const size_t addr = ((size_t)(((bb << 3) + hh) * T_ + tq) << 9) + (cc << 6) + dd;
            *(uint4*)(Y + addr) = dv;
        }
    } else {
        // ---- direct fp32 stores (64B segments per 16-lane group) ----
        const int part = n0 >> 9;                 // uniform per block
        float* Y = part ? (float*)Yi_ : (float*)Yr_;
        #pragma unroll
        for (int nf = 0; nf < 4; ++nf) {
            const int ncol = n0 + wn + nf * 16 + frow;
            const float bv = bias[ncol];
            const int nc = ncol & 511;
            #pragma unroll
            for (int mf = 0; mf < 8; ++mf) {
                const int mb = m0 + wm + mf * 16 + row_l;
                #pragma unroll
                for (int r = 0; r < 4; ++r) {
                    float v = acc[mf][nf][r] + bv;
                    if constexpr (LRELU) v = v >= 0.f ? v : 0.01f * v;
                    Y[(size_t)(mb + r) * 512 + nc] = v;
                }
            }
        }
    }
}

// ---------------------------------------------------------------------
// Attention: per (b,h,t) chunk w = (b*H+h)*T + t, matrices stored as
// 512 contiguous bf16 (c*64+d) at offset w*512.
// ---------------------------------------------------------------------
__global__ __launch_bounds__(256)
void attn_kernel(const u16* __restrict__ qr, const u16* __restrict__ qi,
                 const u16* __restrict__ kr, const u16* __restrict__ ki,
                 const u16* __restrict__ vr, const u16* __restrict__ vi,
                 u16* __restrict__ xr, u16* __restrict__ xi)
{
    constexpr int RS = 68;        // padded row stride (floats)
    constexpr int MS = 8 * RS;    // per matrix: 544 floats
    __shared__ float L[4][6 * MS];     // 52224 B
    __shared__ float S[4][128];        // sr(64) + si(64) per wave

    const int wave = threadIdx.x >> 6;
    const int lane = threadIdx.x & 63;
    const int w    = (blockIdx.x << 2) + wave;   // (b*H+h)*T + t
    const int cl   = lane >> 3;                  // c-index 0..7
    const int dl   = lane & 7;                   // 0..7
    const int d0   = dl << 3;                    // 0,8,..,56

    float* Lw = L[wave];
    const u16* srcs[6] = {qr, qi, kr, ki, vr, vi};
    const size_t gbase = ((size_t)w << 9) + (lane << 3);
    #pragma unroll
    for (int m2 = 0; m2 < 6; ++m2) {
        const uint4 u = *(const uint4*)(srcs[m2] + gbase);
        float* dst = Lw + m2 * MS + cl * RS + d0;
        dst[0]=bflo(u.x); dst[1]=bfhi(u.x);
        dst[2]=bflo(u.y); dst[3]=bfhi(u.y);
        dst[4]=bflo(u.z); dst[5]=bfhi(u.z);
        dst[6]=bflo(u.w); dst[7]=bfhi(u.w);
    }
    __syncthreads();

    { // scores: lane -> (c=cl, e=dl)
        const float* Qr = Lw + 0*MS + cl*RS;
        const float* Qi = Lw + 1*MS + cl*RS;
        const float* Kr = Lw + 2*MS + dl*RS;
        const float* Ki = Lw + 3*MS + dl*RS;
        float srr=0.f, sii=0.f, sri=0.f, sir=0.f;
        #pragma unroll 8
        for (int d = 0; d < 64; ++d) {
            srr = fmaf(Qr[d], Kr[d], srr);
            sii = fmaf(Qi[d], Ki[d], sii);
            sri = fmaf(Qr[d], Ki[d], sri);
            sir = fmaf(Qi[d], Kr[d], sir);
        }
        S[wave][lane]      = (srr + sii) * 0.125f;   // sr[c][e]
        S[wave][64 + lane] = (sri - sir) * 0.125f;   // si[c][e]
    }
    __syncthreads();

    const float* Vr = Lw + 4*MS;
    const float* Vi = Lw + 5*MS;
    const float* Sr = S[wave];
    const float* Si = S[wave] + 64;
    float outr[8] = {}, outi[8] = {};
    #pragma unroll
    for (int e = 0; e < 8; ++e) {
        const float sre = Sr[(cl<<3) + e];
        const float sie = Si[(cl<<3) + e];
        const float* vre = Vr + e*RS + d0;
        const float* vie = Vi + e*RS + d0;
        #pragma unroll
        for (int j = 0; j < 8; ++j) {
            outr[j] = fmaf(sre,  vre[j], outr[j]);
            outr[j] = fmaf(-sie, vie[j], outr[j]);
            outi[j] = fmaf(sie,  vre[j], outi[j]);
            outi[j] = fmaf(sre,  vie[j], outi[j]);
        }
    }

    // write merged (B,C,T,F) bf16 with lrelu
    const int tt = w & 511, hh = (w >> 9) & 7, bb = w >> 12;
    const size_t obase = ((size_t)(((bb << 3) + cl) * T_ + tt) << 9) + (hh << 6) + d0;
    u32 pr[4], pi[4];
    #pragma unroll
    for (int jj = 0; jj < 4; ++jj) {
        float r0 = outr[2*jj], r1 = outr[2*jj+1];
        float i0 = outi[2*jj], i1 = outi[2*jj+1];
        r0 = r0 >= 0.f ? r0 : 0.01f*r0;  r1 = r1 >= 0.f ? r1 : 0.01f*r1;
        i0 = i0 >= 0.f ? i0 : 0.01f*i0;  i1 = i1 >= 0.f ? i1 : 0.01f*i1;
        pr[jj] = (u32)f2bf(r0) | ((u32)f2bf(r1) << 16);
        pi[jj] = (u32)f2bf(i0) | ((u32)f2bf(i1) << 16);
    }
    *(uint4*)(xr + obase) = make_uint4(pr[0], pr[1], pr[2], pr[3]);
    *(uint4*)(xi + obase) = make_uint4(pi[0], pi[1], pi[2], pi[3]);
}

// ---------------------------------------------------------------------
extern "C" void kernel_launch(void* const* d_in, const int* in_sizes, int n_in,
                              void* d_out, int out_size, void* d_ws, size_t ws_size,
                              hipStream_t stream)
{
    (void)in_sizes; (void)n_in; (void)out_size; (void)ws_size;
    const float* act[6];
    for (int i = 0; i < 6; ++i) act[i] = (const float*)d_in[i];

    PrepArgs pa;
    for (int s = 0; s < 4; ++s) {
        pa.wr[s] = (const float*)d_in[6 + s*4 + 0];
        pa.br[s] = (const float*)d_in[6 + s*4 + 1];
        pa.wi[s] = (const float*)d_in[6 + s*4 + 2];
        pa.bi[s] = (const float*)d_in[6 + s*4 + 3];
    }

    const size_t SZ = (size_t)M_ * F_;        // 8,388,608 elements
    u16* ws = (u16*)d_ws;
    u16* a0 = ws + 0*SZ;  u16* a1 = ws + 1*SZ;   // query bf16 -> later k outputs
    u16* a2 = ws + 2*SZ;  u16* a3 = ws + 3*SZ;   // key bf16   -> later v outputs
    u16* a4 = ws + 4*SZ;  u16* a5 = ws + 5*SZ;   // value bf16 -> later attn outputs
    u16* q0 = ws + 6*SZ;  u16* q1 = ws + 7*SZ;   // q outputs
    u16*   wbig = ws + 8*SZ;                      // 4 x 1M bf16
    float* bbig = (float*)(wbig + 4u*1024*1024);  // 4 x 1024 fp32

    ConvArgs ca;
    ca.src[0]=act[0]; ca.src[1]=act[1]; ca.src[2]=act[2];
    ca.src[3]=act[3]; ca.src[4]=act[4]; ca.src[5]=act[5];
    ca.dst[0]=a0; ca.dst[1]=a1; ca.dst[2]=a2; ca.dst[3]=a3; ca.dst[4]=a4; ca.dst[5]=a5;

    convert6_kernel<<<dim3(1024, 6), 256, 0, stream>>>(ca);
    prep_weights_kernel<<<dim3(1024, 4), 256, 0, stream>>>(pa, wbig, bbig);

    dim3 ggrid(M_/256, 1024/256);   // 64 x 4 = 256 blocks = 1/CU
    // q stage
    mfma_clinear256_kernel<true,  false><<<ggrid, 512, 0, stream>>>(
        a0, a1, wbig + 0u*1048576, bbig + 0*1024, q0, q1);
    // k stage (writes into a0/a1, already consumed)
    mfma_clinear256_kernel<true,  false><<<ggrid, 512, 0, stream>>>(
        a2, a3, wbig + 1u*1048576, bbig + 1*1024, a0, a1);
    // v stage with leaky-relu (writes into a2/a3)
    mfma_clinear256_kernel<true,  true ><<<ggrid, 512, 0, stream>>>(
        a4, a5, wbig + 2u*1048576, bbig + 2*1024, a2, a3);

    // attention: q=q0/q1, k=a0/a1, v=a2/a3 -> merged xr=a4, xi=a5
    attn_kernel<<<dim3((B_*H_*T_)/4), 256, 0, stream>>>(q0, q1, a0, a1, a2, a3, a4, a5);

    // output stage: fp32 out, no perm, no lrelu
    float* out_r = (float*)d_out;
    mfma_clinear256_kernel<false, false><<<ggrid, 512, 0, stream>>>(
        a4, a5, wbig + 3u*1048576, bbig + 3*1024, out_r, out_r + SZ);
}